// Round 17
// baseline (71.640 us; speedup 1.0000x reference)
//
#include <hip/hip_runtime.h>
#include <math.h>

#define N_LOC 16384
#define W 128
#define B_SZ 64
#define TOTAL_OUT 390   // 3*W + 6

__device__ __forceinline__ float dot4(float4 a, float4 b) {
    return a.x * b.x + a.y * b.y + a.z * b.z + a.w * b.w;
}
__device__ __forceinline__ float softplus_f(float x) {
    return fmaxf(x, 0.0f) + log1pf(expf(-fabsf(x)));
}
__device__ __forceinline__ float sigmoid_f(float x) {
    return 1.0f / (1.0f + expf(-x));
}
__device__ __forceinline__ float wave_reduce_sum(float v) {
#pragma unroll
    for (int off = 32; off >= 1; off >>= 1) v += __shfl_xor(v, off);
    return v;
}

// ---------------------------------------------------------------------------
// kA (784 blocks = 98 o-quads x 8 b-tiles): one output row per wave, NO LDS,
// no sync. cs rows read straight from L2 (256 KB, hot) -- 36 independent
// coalesced loads per wave, one reduce per b. Minimal serial chain.
// ---------------------------------------------------------------------------
__global__ __launch_bounds__(256) void kA(const float* __restrict__ cs,
                                          const float* __restrict__ fcw,
                                          const float* __restrict__ fcb,
                                          float* __restrict__ raw) {
    const int t = threadIdx.x;
    const int blk = blockIdx.x;
    const int oc = blk % 98;        // 4 outputs each (one per wave)
    const int btile = blk / 98;     // 8 b each

    const int lane = t & 63;
    const int wv = t >> 6;
    const int o = oc * 4 + wv;
    if (o >= TOTAL_OUT) return;

    const float4* fcw4 = reinterpret_cast<const float4*>(fcw);
    const float4* csg = reinterpret_cast<const float4*>(cs);
    float4 r0 = fcw4[o * 256 + 0 * 64 + lane];
    float4 r1 = fcw4[o * 256 + 1 * 64 + lane];
    float4 r2 = fcw4[o * 256 + 2 * 64 + lane];
    float4 r3 = fcw4[o * 256 + 3 * 64 + lane];
    const float bias = fcb[o];
#pragma unroll
    for (int b = 0; b < 8; b++) {
        const float4* cb = csg + (btile * 8 + b) * 256;
        float acc = dot4(cb[0 * 64 + lane], r0);
        acc += dot4(cb[1 * 64 + lane], r1);
        acc += dot4(cb[2 * 64 + lane], r2);
        acc += dot4(cb[3 * 64 + lane], r3);
        acc = wave_reduce_sum(acc);
        if (lane == 0) {
            raw[(btile * 8 + b) * TOTAL_OUT + o] = acc + bias;
        }
    }
}

// ---------------------------------------------------------------------------
// kB (512 blocks, 32 n each; thread = (bg 0..31, ns 0..7) -> 2 b x 4 n):
// each LDS key read feeds 4 dots (R16: 2) -> ds_read_b128 wave-instructions
// halve again. Per instruction a wave reads 8 distinct kb4 rows at 2-row
// stride (264 dwords = 8 mod 32) -> 16B chunks on bank offsets {0,8,16,24},
// duplicates broadcast -> conflict-free. Global rows L1-dedup'd as before.
// Grid/TLP unchanged vs R16 (512 blocks, 2/CU, 8 waves/CU).
// ---------------------------------------------------------------------------
__global__ __launch_bounds__(256) void kB(const float* __restrict__ mem,
                                          const float* __restrict__ raw,
                                          float* __restrict__ e_buf,
                                          float* __restrict__ partialS) {
    __shared__ float4 kb4[B_SZ][33];   // padded row: 528B stride
    __shared__ float betaS[B_SZ];
    const int t = threadIdx.x;
    const int blk = blockIdx.x;

    {   // build scaled key fragments: b = t>>2, 32 key elems per thread
        const int b = t >> 2;
        const int q = t & 3;
        const float* rb = raw + b * TOTAL_OUT;
        const float2* rk = reinterpret_cast<const float2*>(rb) + q * 16;
        float2 v[16];
        float ss = 0.0f;
#pragma unroll
        for (int j = 0; j < 16; j++) {
            v[j] = rk[j];
            ss += v[j].x * v[j].x + v[j].y * v[j].y;
        }
        ss += __shfl_xor(ss, 1);
        ss += __shfl_xor(ss, 2);
        const float beta = softplus_f(rb[W]);
        const float scale = beta / fmaxf(sqrtf(ss), 1e-12f);
        if (q == 0) betaS[b] = beta;
#pragma unroll
        for (int jj = 0; jj < 8; jj++) {
            kb4[b][q * 8 + jj] = make_float4(v[2 * jj].x * scale,
                                             v[2 * jj].y * scale,
                                             v[2 * jj + 1].x * scale,
                                             v[2 * jj + 1].y * scale);
        }
    }
    __syncthreads();

    const int ns = t & 7;              // 0..7
    const int bg = t >> 3;             // 0..31 -> b = bg*2 + bi
    const int n0 = blk * 32 + ns;      // rows n0 + {0,8,16,24}
    const float4* memg = reinterpret_cast<const float4*>(mem);
    const float4* mr0 = memg + (size_t)(n0 + 0) * 32;
    const float4* mr1 = memg + (size_t)(n0 + 8) * 32;
    const float4* mr2 = memg + (size_t)(n0 + 16) * 32;
    const float4* mr3 = memg + (size_t)(n0 + 24) * 32;

    float acc[2][4];
#pragma unroll
    for (int bi = 0; bi < 2; bi++)
#pragma unroll
        for (int j = 0; j < 4; j++) acc[bi][j] = 0.0f;
    float nrm[4] = {0.0f, 0.0f, 0.0f, 0.0f};

#pragma unroll 8
    for (int k4 = 0; k4 < 32; k4++) {
        float4 mv0 = mr0[k4];
        float4 mv1 = mr1[k4];
        float4 mv2 = mr2[k4];
        float4 mv3 = mr3[k4];
        nrm[0] += dot4(mv0, mv0);
        nrm[1] += dot4(mv1, mv1);
        nrm[2] += dot4(mv2, mv2);
        nrm[3] += dot4(mv3, mv3);
#pragma unroll
        for (int bi = 0; bi < 2; bi++) {
            float4 kv = kb4[bg * 2 + bi][k4];   // broadcast across 8 ns lanes
            acc[bi][0] += dot4(kv, mv0);
            acc[bi][1] += dot4(kv, mv1);
            acc[bi][2] += dot4(kv, mv2);
            acc[bi][3] += dot4(kv, mv3);
        }
    }
    float r[4];
#pragma unroll
    for (int j = 0; j < 4; j++) r[j] = 1.0f / fmaxf(sqrtf(nrm[j]), 1e-12f);

    float ev[2];
#pragma unroll
    for (int bi = 0; bi < 2; bi++) {
        const int b = bg * 2 + bi;
        float s = 0.0f;
#pragma unroll
        for (int j = 0; j < 4; j++) {
            float e = __expf(acc[bi][j] * r[j] - betaS[b]);
            e_buf[(size_t)b * N_LOC + n0 + j * 8] = e;
            s += e;
        }
        ev[bi] = s;
    }
    // sum over the 8 ns lanes (xor offsets stay within the 8-lane group)
#pragma unroll
    for (int bi = 0; bi < 2; bi++) {
        float v = ev[bi];
        v += __shfl_xor(v, 1);
        v += __shfl_xor(v, 2);
        v += __shfl_xor(v, 4);
        ev[bi] = v;
    }
    if (ns == 0) {
#pragma unroll
        for (int bi = 0; bi < 2; bi++)
            partialS[(size_t)(bg * 2 + bi) * 512 + blk] = ev[bi];
    }
}

// ---------------------------------------------------------------------------
// kC (512 blocks = 64 b x 8 chunks of 2048): per-b scalars from raw;
// S-reduce over 512 partials (fixed order); gate-mix; circular 3-tap shift
// (scalar halo); sharpen; write unnormalized p + partialP[b][8]; c==0 blocks
// also emit erase/addv activations for kD.
// ---------------------------------------------------------------------------
__global__ __launch_bounds__(256) void kC(const float* __restrict__ e_buf,
                                          const float* __restrict__ wprev,
                                          const float* __restrict__ raw,
                                          const float* __restrict__ partialS,
                                          float* __restrict__ p_buf,
                                          float* __restrict__ partialP,
                                          float* __restrict__ erase,
                                          float* __restrict__ addv) {
    __shared__ float rC[4];
    __shared__ float cpar[5];   // gate, gamma, sh0, sh1, sh2
    const int t = threadIdx.x;
    const int blk = blockIdx.x;
    const int b = blk >> 3, c = blk & 7;
    const float* rb = raw + b * TOTAL_OUT;

    const float* ps = partialS + (size_t)b * 512;
    float sv = ps[t] + ps[t + 256];
    sv = wave_reduce_sum(sv);
    if ((t & 63) == 0) rC[t >> 6] = sv;
    if (t == 0) {
        cpar[0] = sigmoid_f(rb[W + 1]);
        cpar[1] = softplus_f(rb[W + 5]) + 1.0f;
        float s0 = rb[W + 2], s1 = rb[W + 3], s2 = rb[W + 4];
        float m = fmaxf(s0, fmaxf(s1, s2));
        float e0 = expf(s0 - m), e1 = expf(s1 - m), e2 = expf(s2 - m);
        float si = 1.0f / (e0 + e1 + e2);
        cpar[2] = e0 * si;
        cpar[3] = e1 * si;
        cpar[4] = e2 * si;
    }
    __syncthreads();
    const float S = rC[0] + rC[1] + rC[2] + rC[3];

    const float gate = cpar[0];
    const float ga = gate / S;
    const float og = 1.0f - gate;
    const float gm = cpar[1];
    const float sh0 = cpar[2];
    const float sh1 = cpar[3];
    const float sh2 = cpar[4];

    if (c == 0) {   // erase/add activations for kD (1 elem/thread)
        if (t < 128) erase[b * W + t] = sigmoid_f(rb[W + 6 + t]);
        else         addv[b * W + (t - 128)] = tanhf(rb[2 * W + 6 + (t - 128)]);
    }

    const float* erow = e_buf + (size_t)b * N_LOC;
    const float* wrow = wprev + (size_t)b * N_LOC;
    const int nb = c * 2048 + 8 * t;

    float4 e0v = *reinterpret_cast<const float4*>(erow + nb);
    float4 e1v = *reinterpret_cast<const float4*>(erow + nb + 4);
    float4 w0 = *reinterpret_cast<const float4*>(wrow + nb);
    float4 w1 = *reinterpret_cast<const float4*>(wrow + nb + 4);
    const int nm1 = (nb + N_LOC - 1) & (N_LOC - 1);
    const int np8 = (nb + 8) & (N_LOC - 1);

    float g[10];
    g[0] = ga * erow[nm1] + og * wrow[nm1];
    g[1] = ga * e0v.x + og * w0.x;
    g[2] = ga * e0v.y + og * w0.y;
    g[3] = ga * e0v.z + og * w0.z;
    g[4] = ga * e0v.w + og * w0.w;
    g[5] = ga * e1v.x + og * w1.x;
    g[6] = ga * e1v.y + og * w1.y;
    g[7] = ga * e1v.z + og * w1.z;
    g[8] = ga * e1v.w + og * w1.w;
    g[9] = ga * erow[np8] + og * wrow[np8];

    float p[8];
    float sp = 0.0f;
#pragma unroll
    for (int j = 0; j < 8; j++) {
        float x = fmaxf(sh0 * g[j] + sh1 * g[j + 1] + sh2 * g[j + 2], 1e-9f);
        p[j] = exp2f(gm * __log2f(x));
        sp += p[j];
    }
    *reinterpret_cast<float4*>(p_buf + (size_t)b * N_LOC + nb) =
        make_float4(p[0], p[1], p[2], p[3]);
    *reinterpret_cast<float4*>(p_buf + (size_t)b * N_LOC + nb + 4) =
        make_float4(p[4], p[5], p[6], p[7]);

    sp = wave_reduce_sum(sp);
    __syncthreads();
    if ((t & 63) == 0) rC[t >> 6] = sp;
    __syncthreads();
    if (t == 0) partialP[b * 8 + c] = rC[0] + rC[1] + rC[2] + rC[3];
}

// ---------------------------------------------------------------------------
// kD (512 blocks, 32 n each): invb via fixed-order sums; erase/addv staged in
// LDS; b-loop unrolled x8 so 32 p-broadcast loads are in flight; memory
// update; in-place normalize p -> w_new. Add order preserved -> deterministic.
// ---------------------------------------------------------------------------
__global__ __launch_bounds__(256) void kD(const float* __restrict__ mem,
                                          const float* __restrict__ erase,
                                          const float* __restrict__ addv,
                                          const float* __restrict__ partialP,
                                          float* __restrict__ p_buf,
                                          float* __restrict__ outmem) {
    __shared__ float invb[B_SZ];
    __shared__ float eL[B_SZ][W];      // 32 KB
    __shared__ float aL[B_SZ][W];      // 32 KB
    const int t = threadIdx.x;
    const int blk = blockIdx.x;
    if (t < B_SZ) {
        const float* pp = partialP + t * 8;
        float s = 0.0f;
#pragma unroll
        for (int j = 0; j < 8; j++) s += pp[j];
        invb[t] = 1.0f / (s + 1e-9f);
    }
    // stage erase/addv: 8192 floats each, 256 threads -> 32 float4s per thread
    {
        const float4* eg = reinterpret_cast<const float4*>(erase);
        const float4* ag = reinterpret_cast<const float4*>(addv);
        float4* el4 = reinterpret_cast<float4*>(&eL[0][0]);
        float4* al4 = reinterpret_cast<float4*>(&aL[0][0]);
#pragma unroll
        for (int i = 0; i < 8; i++) {
            el4[t + 256 * i] = eg[t + 256 * i];
            al4[t + 256 * i] = ag[t + 256 * i];
        }
    }
    __syncthreads();

    const int w = t & 127;
    const int nh = t >> 7;
    const int nb = blk * 32;
    const int nbase = nb + nh * 16;

    float ae[16], aa[16];
#pragma unroll
    for (int i = 0; i < 16; i++) { ae[i] = 0.0f; aa[i] = 0.0f; }

#pragma unroll 8
    for (int b = 0; b < B_SZ; b++) {
        const float ib = invb[b] * (1.0f / 64.0f);
        const float wei = eL[b][w] * ib;
        const float wai = aL[b][w] * ib;
        const float4* pr4 =
            reinterpret_cast<const float4*>(p_buf + (size_t)b * N_LOC + nbase);
#pragma unroll
        for (int i4 = 0; i4 < 4; i4++) {
            float4 v = pr4[i4];
            ae[i4 * 4 + 0] += v.x * wei; aa[i4 * 4 + 0] += v.x * wai;
            ae[i4 * 4 + 1] += v.y * wei; aa[i4 * 4 + 1] += v.y * wai;
            ae[i4 * 4 + 2] += v.z * wei; aa[i4 * 4 + 2] += v.z * wai;
            ae[i4 * 4 + 3] += v.w * wei; aa[i4 * 4 + 3] += v.w * wai;
        }
    }
#pragma unroll
    for (int i = 0; i < 16; i++) {
        const int n = nbase + i;
        float mv = mem[(size_t)n * W + w];
        outmem[(size_t)n * W + w] = mv * (1.0f - ae[i]) + aa[i];
    }
    __syncthreads();   // all accumulation reads of p done before overwrite
    const int b8 = t >> 5, nl = t & 31;
#pragma unroll
    for (int bi = 0; bi < 8; bi++) {
        const int b = bi * 8 + b8;
        const size_t idx = (size_t)b * N_LOC + nb + nl;
        p_buf[idx] *= invb[b];
    }
}

// ---------------------------------------------------------------------------
extern "C" void kernel_launch(void* const* d_in, const int* in_sizes, int n_in,
                              void* d_out, int out_size, void* d_ws, size_t ws_size,
                              hipStream_t stream) {
    const float* cs    = (const float*)d_in[0];   // (64, 1024)
    const float* mem   = (const float*)d_in[1];   // (16384, 128)
    const float* wprev = (const float*)d_in[2];   // (64, 16384)
    const float* fcw   = (const float*)d_in[3];   // (390, 1024)
    const float* fcb   = (const float*)d_in[4];   // (390,)

    float* out = (float*)d_out;
    float* p_buf = out;                                  // (64,16384): p -> w_new
    float* emem = out + (size_t)B_SZ * N_LOC;            // e_buf, then new_memory

    float* wsf = (float*)d_ws;
    float* raw      = wsf;               // 24960 floats
    float* erase    = raw + 24960;       // 8192
    float* addv     = erase + 8192;      // 8192
    float* partialS = addv + 8192;       // 64*512 = 32768
    float* partialP = partialS + 32768;  // 64*8 = 512

    kA<<<784, 256, 0, stream>>>(cs, fcw, fcb, raw);
    kB<<<512, 256, 0, stream>>>(mem, raw, emem, partialS);
    kC<<<512, 256, 0, stream>>>(emem, wprev, raw, partialS, p_buf, partialP,
                                erase, addv);
    kD<<<512, 256, 0, stream>>>(mem, erase, addv, partialP, p_buf, emem);
}

// Round 18
// 57.331 us; speedup vs baseline: 1.2496x; 1.2496x over previous
//
#include <hip/hip_runtime.h>
#include <math.h>

#define N_LOC 16384
#define W 128
#define B_SZ 64
#define TOTAL_OUT 390   // 3*W + 6

__device__ __forceinline__ float dot4(float4 a, float4 b) {
    return a.x * b.x + a.y * b.y + a.z * b.z + a.w * b.w;
}
__device__ __forceinline__ float softplus_f(float x) {
    return fmaxf(x, 0.0f) + log1pf(expf(-fabsf(x)));
}
__device__ __forceinline__ float sigmoid_f(float x) {
    return 1.0f / (1.0f + expf(-x));
}
__device__ __forceinline__ float wave_reduce_sum(float v) {
#pragma unroll
    for (int off = 32; off >= 1; off >>= 1) v += __shfl_xor(v, off);
    return v;
}

// ---------------------------------------------------------------------------
// kA (784 blocks = 98 o-quads x 8 b-tiles): one output row per wave, NO LDS,
// no sync. cs rows read straight from L2 (256 KB, hot) -- 36 independent
// coalesced loads per wave, one reduce per b. Minimal serial chain.
// ---------------------------------------------------------------------------
__global__ __launch_bounds__(256) void kA(const float* __restrict__ cs,
                                          const float* __restrict__ fcw,
                                          const float* __restrict__ fcb,
                                          float* __restrict__ raw) {
    const int t = threadIdx.x;
    const int blk = blockIdx.x;
    const int oc = blk % 98;        // 4 outputs each (one per wave)
    const int btile = blk / 98;     // 8 b each

    const int lane = t & 63;
    const int wv = t >> 6;
    const int o = oc * 4 + wv;
    if (o >= TOTAL_OUT) return;

    const float4* fcw4 = reinterpret_cast<const float4*>(fcw);
    const float4* csg = reinterpret_cast<const float4*>(cs);
    float4 r0 = fcw4[o * 256 + 0 * 64 + lane];
    float4 r1 = fcw4[o * 256 + 1 * 64 + lane];
    float4 r2 = fcw4[o * 256 + 2 * 64 + lane];
    float4 r3 = fcw4[o * 256 + 3 * 64 + lane];
    const float bias = fcb[o];
#pragma unroll
    for (int b = 0; b < 8; b++) {
        const float4* cb = csg + (btile * 8 + b) * 256;
        float acc = dot4(cb[0 * 64 + lane], r0);
        acc += dot4(cb[1 * 64 + lane], r1);
        acc += dot4(cb[2 * 64 + lane], r2);
        acc += dot4(cb[3 * 64 + lane], r3);
        acc = wave_reduce_sum(acc);
        if (lane == 0) {
            raw[(btile * 8 + b) * TOTAL_OUT + o] = acc + bias;
        }
    }
}

// ---------------------------------------------------------------------------
// kB (512 blocks, 32 n each; thread = (bg 0..15, ns 0..15) -> 4 b x 2 n):
// each LDS key read feeds 2 dots; 2 global loads per k4 keep the wave's
// vector-memory instruction at 16 distinct rows / 256B useful per issue
// (R17's 4-load variant halved that and regressed 14us -> reverted).
// kb4 row padded to 33 float4s (2-way worst-case on banks, free per m136).
// ---------------------------------------------------------------------------
__global__ __launch_bounds__(256) void kB(const float* __restrict__ mem,
                                          const float* __restrict__ raw,
                                          float* __restrict__ e_buf,
                                          float* __restrict__ partialS) {
    __shared__ float4 kb4[B_SZ][33];   // padded row: 528B stride
    __shared__ float betaS[B_SZ];
    const int t = threadIdx.x;
    const int blk = blockIdx.x;

    {   // build scaled key fragments: b = t>>2, 32 key elems per thread
        const int b = t >> 2;
        const int q = t & 3;
        const float* rb = raw + b * TOTAL_OUT;
        const float2* rk = reinterpret_cast<const float2*>(rb) + q * 16;
        float2 v[16];
        float ss = 0.0f;
#pragma unroll
        for (int j = 0; j < 16; j++) {
            v[j] = rk[j];
            ss += v[j].x * v[j].x + v[j].y * v[j].y;
        }
        ss += __shfl_xor(ss, 1);
        ss += __shfl_xor(ss, 2);
        const float beta = softplus_f(rb[W]);
        const float scale = beta / fmaxf(sqrtf(ss), 1e-12f);
        if (q == 0) betaS[b] = beta;
#pragma unroll
        for (int jj = 0; jj < 8; jj++) {
            kb4[b][q * 8 + jj] = make_float4(v[2 * jj].x * scale,
                                             v[2 * jj].y * scale,
                                             v[2 * jj + 1].x * scale,
                                             v[2 * jj + 1].y * scale);
        }
    }
    __syncthreads();

    const int ns = t & 15;             // 0..15
    const int bg = t >> 4;             // 0..15 -> b = bg*4 + bi
    const int n0 = blk * 32 + ns;
    const int n1 = n0 + 16;
    const float4* mrow0 = reinterpret_cast<const float4*>(mem) + (size_t)n0 * 32;
    const float4* mrow1 = reinterpret_cast<const float4*>(mem) + (size_t)n1 * 32;

    float acc0[4], acc1[4];
#pragma unroll
    for (int i = 0; i < 4; i++) { acc0[i] = 0.0f; acc1[i] = 0.0f; }
    float nrm0 = 0.0f, nrm1 = 0.0f;
#pragma unroll 8
    for (int k4 = 0; k4 < 32; k4++) {
        float4 mv0 = mrow0[k4];
        float4 mv1 = mrow1[k4];
        nrm0 += dot4(mv0, mv0);
        nrm1 += dot4(mv1, mv1);
#pragma unroll
        for (int bi = 0; bi < 4; bi++) {
            float4 kv = kb4[bg * 4 + bi][k4];   // broadcast across 16 ns lanes
            acc0[bi] += dot4(kv, mv0);
            acc1[bi] += dot4(kv, mv1);
        }
    }
    const float r0 = 1.0f / fmaxf(sqrtf(nrm0), 1e-12f);
    const float r1 = 1.0f / fmaxf(sqrtf(nrm1), 1e-12f);
    float ev[4];
#pragma unroll
    for (int bi = 0; bi < 4; bi++) {
        const int b = bg * 4 + bi;
        float e0 = __expf(acc0[bi] * r0 - betaS[b]);
        float e1 = __expf(acc1[bi] * r1 - betaS[b]);
        e_buf[(size_t)b * N_LOC + n0] = e0;
        e_buf[(size_t)b * N_LOC + n1] = e1;
        ev[bi] = e0 + e1;
    }
    // sum over the 16 ns lanes (xor offsets stay within the 16-lane group)
#pragma unroll
    for (int bi = 0; bi < 4; bi++) {
        float v = ev[bi];
        v += __shfl_xor(v, 1);
        v += __shfl_xor(v, 2);
        v += __shfl_xor(v, 4);
        v += __shfl_xor(v, 8);
        ev[bi] = v;
    }
    if (ns == 0) {
#pragma unroll
        for (int bi = 0; bi < 4; bi++)
            partialS[(size_t)(bg * 4 + bi) * 512 + blk] = ev[bi];
    }
}

// ---------------------------------------------------------------------------
// kC (512 blocks = 64 b x 8 chunks of 2048): per-b scalars from raw;
// S-reduce over 512 partials (fixed order); gate-mix; circular 3-tap shift
// (scalar halo); sharpen; write unnormalized p + partialP[b][8]; c==0 blocks
// also emit erase/addv activations for kD.
// ---------------------------------------------------------------------------
__global__ __launch_bounds__(256) void kC(const float* __restrict__ e_buf,
                                          const float* __restrict__ wprev,
                                          const float* __restrict__ raw,
                                          const float* __restrict__ partialS,
                                          float* __restrict__ p_buf,
                                          float* __restrict__ partialP,
                                          float* __restrict__ erase,
                                          float* __restrict__ addv) {
    __shared__ float rC[4];
    __shared__ float cpar[5];   // gate, gamma, sh0, sh1, sh2
    const int t = threadIdx.x;
    const int blk = blockIdx.x;
    const int b = blk >> 3, c = blk & 7;
    const float* rb = raw + b * TOTAL_OUT;

    const float* ps = partialS + (size_t)b * 512;
    float sv = ps[t] + ps[t + 256];
    sv = wave_reduce_sum(sv);
    if ((t & 63) == 0) rC[t >> 6] = sv;
    if (t == 0) {
        cpar[0] = sigmoid_f(rb[W + 1]);
        cpar[1] = softplus_f(rb[W + 5]) + 1.0f;
        float s0 = rb[W + 2], s1 = rb[W + 3], s2 = rb[W + 4];
        float m = fmaxf(s0, fmaxf(s1, s2));
        float e0 = expf(s0 - m), e1 = expf(s1 - m), e2 = expf(s2 - m);
        float si = 1.0f / (e0 + e1 + e2);
        cpar[2] = e0 * si;
        cpar[3] = e1 * si;
        cpar[4] = e2 * si;
    }
    __syncthreads();
    const float S = rC[0] + rC[1] + rC[2] + rC[3];

    const float gate = cpar[0];
    const float ga = gate / S;
    const float og = 1.0f - gate;
    const float gm = cpar[1];
    const float sh0 = cpar[2];
    const float sh1 = cpar[3];
    const float sh2 = cpar[4];

    if (c == 0) {   // erase/add activations for kD (1 elem/thread)
        if (t < 128) erase[b * W + t] = sigmoid_f(rb[W + 6 + t]);
        else         addv[b * W + (t - 128)] = tanhf(rb[2 * W + 6 + (t - 128)]);
    }

    const float* erow = e_buf + (size_t)b * N_LOC;
    const float* wrow = wprev + (size_t)b * N_LOC;
    const int nb = c * 2048 + 8 * t;

    float4 e0v = *reinterpret_cast<const float4*>(erow + nb);
    float4 e1v = *reinterpret_cast<const float4*>(erow + nb + 4);
    float4 w0 = *reinterpret_cast<const float4*>(wrow + nb);
    float4 w1 = *reinterpret_cast<const float4*>(wrow + nb + 4);
    const int nm1 = (nb + N_LOC - 1) & (N_LOC - 1);
    const int np8 = (nb + 8) & (N_LOC - 1);

    float g[10];
    g[0] = ga * erow[nm1] + og * wrow[nm1];
    g[1] = ga * e0v.x + og * w0.x;
    g[2] = ga * e0v.y + og * w0.y;
    g[3] = ga * e0v.z + og * w0.z;
    g[4] = ga * e0v.w + og * w0.w;
    g[5] = ga * e1v.x + og * w1.x;
    g[6] = ga * e1v.y + og * w1.y;
    g[7] = ga * e1v.z + og * w1.z;
    g[8] = ga * e1v.w + og * w1.w;
    g[9] = ga * erow[np8] + og * wrow[np8];

    float p[8];
    float sp = 0.0f;
#pragma unroll
    for (int j = 0; j < 8; j++) {
        float x = fmaxf(sh0 * g[j] + sh1 * g[j + 1] + sh2 * g[j + 2], 1e-9f);
        p[j] = exp2f(gm * __log2f(x));
        sp += p[j];
    }
    *reinterpret_cast<float4*>(p_buf + (size_t)b * N_LOC + nb) =
        make_float4(p[0], p[1], p[2], p[3]);
    *reinterpret_cast<float4*>(p_buf + (size_t)b * N_LOC + nb + 4) =
        make_float4(p[4], p[5], p[6], p[7]);

    sp = wave_reduce_sum(sp);
    __syncthreads();
    if ((t & 63) == 0) rC[t >> 6] = sp;
    __syncthreads();
    if (t == 0) partialP[b * 8 + c] = rC[0] + rC[1] + rC[2] + rC[3];
}

// ---------------------------------------------------------------------------
// kD (512 blocks, 32 n each): invb via fixed-order sums; erase/addv staged in
// LDS; b-loop unrolled x4 so 16 p-broadcast loads are in flight; memory
// update; in-place normalize p -> w_new. Add order preserved -> deterministic.
// ---------------------------------------------------------------------------
__global__ __launch_bounds__(256) void kD(const float* __restrict__ mem,
                                          const float* __restrict__ erase,
                                          const float* __restrict__ addv,
                                          const float* __restrict__ partialP,
                                          float* __restrict__ p_buf,
                                          float* __restrict__ outmem) {
    __shared__ float invb[B_SZ];
    __shared__ float eL[B_SZ][W];      // 32 KB
    __shared__ float aL[B_SZ][W];      // 32 KB
    const int t = threadIdx.x;
    const int blk = blockIdx.x;
    if (t < B_SZ) {
        const float* pp = partialP + t * 8;
        float s = 0.0f;
#pragma unroll
        for (int j = 0; j < 8; j++) s += pp[j];
        invb[t] = 1.0f / (s + 1e-9f);
    }
    // stage erase/addv: 8192 floats each, 256 threads -> 32 float4s per thread
    {
        const float4* eg = reinterpret_cast<const float4*>(erase);
        const float4* ag = reinterpret_cast<const float4*>(addv);
        float4* el4 = reinterpret_cast<float4*>(&eL[0][0]);
        float4* al4 = reinterpret_cast<float4*>(&aL[0][0]);
#pragma unroll
        for (int i = 0; i < 8; i++) {
            el4[t + 256 * i] = eg[t + 256 * i];
            al4[t + 256 * i] = ag[t + 256 * i];
        }
    }
    __syncthreads();

    const int w = t & 127;
    const int nh = t >> 7;
    const int nb = blk * 32;
    const int nbase = nb + nh * 16;

    float ae[16], aa[16];
#pragma unroll
    for (int i = 0; i < 16; i++) { ae[i] = 0.0f; aa[i] = 0.0f; }

#pragma unroll 4
    for (int b = 0; b < B_SZ; b++) {
        const float ib = invb[b] * (1.0f / 64.0f);
        const float wei = eL[b][w] * ib;
        const float wai = aL[b][w] * ib;
        const float4* pr4 =
            reinterpret_cast<const float4*>(p_buf + (size_t)b * N_LOC + nbase);
#pragma unroll
        for (int i4 = 0; i4 < 4; i4++) {
            float4 v = pr4[i4];
            ae[i4 * 4 + 0] += v.x * wei; aa[i4 * 4 + 0] += v.x * wai;
            ae[i4 * 4 + 1] += v.y * wei; aa[i4 * 4 + 1] += v.y * wai;
            ae[i4 * 4 + 2] += v.z * wei; aa[i4 * 4 + 2] += v.z * wai;
            ae[i4 * 4 + 3] += v.w * wei; aa[i4 * 4 + 3] += v.w * wai;
        }
    }
#pragma unroll
    for (int i = 0; i < 16; i++) {
        const int n = nbase + i;
        float mv = mem[(size_t)n * W + w];
        outmem[(size_t)n * W + w] = mv * (1.0f - ae[i]) + aa[i];
    }
    __syncthreads();   // all accumulation reads of p done before overwrite
    const int b8 = t >> 5, nl = t & 31;
#pragma unroll
    for (int bi = 0; bi < 8; bi++) {
        const int b = bi * 8 + b8;
        const size_t idx = (size_t)b * N_LOC + nb + nl;
        p_buf[idx] *= invb[b];
    }
}

// ---------------------------------------------------------------------------
extern "C" void kernel_launch(void* const* d_in, const int* in_sizes, int n_in,
                              void* d_out, int out_size, void* d_ws, size_t ws_size,
                              hipStream_t stream) {
    const float* cs    = (const float*)d_in[0];   // (64, 1024)
    const float* mem   = (const float*)d_in[1];   // (16384, 128)
    const float* wprev = (const float*)d_in[2];   // (64, 16384)
    const float* fcw   = (const float*)d_in[3];   // (390, 1024)
    const float* fcb   = (const float*)d_in[4];   // (390,)

    float* out = (float*)d_out;
    float* p_buf = out;                                  // (64,16384): p -> w_new
    float* emem = out + (size_t)B_SZ * N_LOC;            // e_buf, then new_memory

    float* wsf = (float*)d_ws;
    float* raw      = wsf;               // 24960 floats
    float* erase    = raw + 24960;       // 8192
    float* addv     = erase + 8192;      // 8192
    float* partialS = addv + 8192;       // 64*512 = 32768
    float* partialP = partialS + 32768;  // 64*8 = 512

    kA<<<784, 256, 0, stream>>>(cs, fcw, fcb, raw);
    kB<<<512, 256, 0, stream>>>(mem, raw, emem, partialS);
    kC<<<512, 256, 0, stream>>>(emem, wprev, raw, partialS, p_buf, partialP,
                                erase, addv);
    kD<<<512, 256, 0, stream>>>(mem, erase, addv, partialP, p_buf, emem);
}